// Round 15
// baseline (416.885 us; speedup 1.0000x reference)
//
#include <hip/hip_runtime.h>
#include <hip/hip_bf16.h>

typedef __attribute__((ext_vector_type(8))) short short8;
typedef __attribute__((ext_vector_type(4))) short short4v;
typedef __attribute__((ext_vector_type(4))) float f32x4;

#define NR 8192
#define LOG2E 1.4426950408889634f

__device__ __forceinline__ short f2bf(float f) {
  return __builtin_bit_cast(short, __float2bfloat16(f));
}

// ---------------------------------------------------------------------------
// K1: HT2 = (x @ W)^T in bf16, tiled layout HT2[j>>5][f][j&31] (tile =
// 128x32 bf16 = 8 KB). Fused s,t epilogue (log2e folded). ~10 us.
// ---------------------------------------------------------------------------
__global__ __launch_bounds__(256) void k_gemm_h(const float* __restrict__ x,
                                                const float* __restrict__ W,
                                                const float* __restrict__ a,
                                                short* __restrict__ HT2,
                                                float* __restrict__ sv,
                                                float* __restrict__ tv) {
  __shared__ short WT[128][136];  // pad 8 shorts -> 2-way alias (free, m136)
  const int tid = threadIdx.x;
  const int w = tid >> 6;
  const int L = tid & 63;
  const int lm = L & 15;
  const int q = L >> 4;
  const int i0 = blockIdx.x * 64;

  f32x4 acc[8];
#pragma unroll
  for (int nn = 0; nn < 8; ++nn) acc[nn] = (f32x4){0.f, 0.f, 0.f, 0.f};

  for (int kc = 0; kc < 256; kc += 128) {
    if (kc) __syncthreads();
#pragma unroll
    for (int p = 0; p < 16; ++p) {
      int idx = p * 256 + tid;  // 0..4095
      int k = idx >> 5;         // 0..127
      int f4 = (idx & 31) * 4;
      float4 v = *(const float4*)&W[(kc + k) * 128 + f4];
      WT[f4 + 0][k] = f2bf(v.x);
      WT[f4 + 1][k] = f2bf(v.y);
      WT[f4 + 2][k] = f2bf(v.z);
      WT[f4 + 3][k] = f2bf(v.w);
    }
    __syncthreads();
#pragma unroll
    for (int ks = 0; ks < 4; ++ks) {
      int row = i0 + 16 * w + lm;
      const float* xp = &x[(size_t)row * 256 + kc + ks * 32 + q * 8];
      float4 xa = *(const float4*)xp;
      float4 xb = *(const float4*)(xp + 4);
      short8 af;
      af[0] = f2bf(xa.x); af[1] = f2bf(xa.y); af[2] = f2bf(xa.z); af[3] = f2bf(xa.w);
      af[4] = f2bf(xb.x); af[5] = f2bf(xb.y); af[6] = f2bf(xb.z); af[7] = f2bf(xb.w);
#pragma unroll
      for (int nn = 0; nn < 8; ++nn) {
        short8 bf = *(const short8*)&WT[nn * 16 + lm][ks * 32 + q * 8];
        acc[nn] = __builtin_amdgcn_mfma_f32_16x16x32_bf16(af, bf, acc[nn], 0, 0, 0);
      }
    }
  }

  const int ib = i0 + 16 * w + 4 * q;  // this thread's 4 output j-rows
  const int tbase = (ib >> 5) * 4096 + (ib & 31);
  float a1v[8], a2v[8];
#pragma unroll
  for (int nn = 0; nn < 8; ++nn) {
    a1v[nn] = a[nn * 16 + lm];
    a2v[nn] = a[128 + nn * 16 + lm];
  }
  float sr[4] = {0.f, 0.f, 0.f, 0.f};
  float tr[4] = {0.f, 0.f, 0.f, 0.f};
#pragma unroll
  for (int nn = 0; nn < 8; ++nn) {
    int f = nn * 16 + lm;
    short4v o;
    o[0] = f2bf(acc[nn][0]);
    o[1] = f2bf(acc[nn][1]);
    o[2] = f2bf(acc[nn][2]);
    o[3] = f2bf(acc[nn][3]);
    *(short4v*)&HT2[tbase + f * 32] = o;
#pragma unroll
    for (int r = 0; r < 4; ++r) {
      sr[r] += acc[nn][r] * a1v[nn];
      tr[r] += acc[nn][r] * a2v[nn];
    }
  }
#pragma unroll
  for (int d = 1; d < 16; d <<= 1) {
#pragma unroll
    for (int r = 0; r < 4; ++r) {
      sr[r] += __shfl_xor(sr[r], d);
      tr[r] += __shfl_xor(tr[r], d);
    }
  }
  if (lm == 0) {
#pragma unroll
    for (int r = 0; r < 4; ++r) {
      sv[ib + r] = sr[r] * LOG2E;
      tv[ib + r] = tr[r] * LOG2E;
    }
  }
}

// ---------------------------------------------------------------------------
// K3: flash-GAT, R14 structure + DEEP adj PREFETCH (the last in-loop global
// latency). Block = 512 thr (8 waves x 16 rows); 16 waves/CU; 66 KB LDS
// (2 blocks/CU). Inner loop global traffic: ONLY adj, prefetched 4 TILES
// AHEAD (4x~250 cyc of compute in flight >= ~900 cyc HBM latency; 8
// outstanding vmem/wave). tv staged once to LDS (broadcast ds_reads). HT2
// slice staged in 2 phases of 8 tiles, natural layout (bank-uniform for
// b128 reads - swizzle unnecessary by bank arithmetic). Full unroll.
// ---------------------------------------------------------------------------
__global__ __launch_bounds__(512, 4) void k_flash(const int* __restrict__ adj,
                                                  const short* __restrict__ HT2,
                                                  const float* __restrict__ sv,
                                                  const float* __restrict__ tv,
                                                  float* __restrict__ part,
                                                  float* __restrict__ lpart) {
  __shared__ short lds_s[32768];  // 64 KB: 8 tiles x 8 KB (natural layout)
  __shared__ float ltv[512];      // 2 KB: whole slice's tv
  const int tid = threadIdx.x;
  const int w = tid >> 6;  // 0..7
  const int L = tid & 63;
  const int lm = L & 15;
  const int q = L >> 4;
  const int sp = blockIdx.x & 15;  // j-split
  const int it = blockIdx.x >> 4;  // i-tile (64 x 128 rows)
  const int i0 = it * 128;

  const int row0 = i0 + 16 * w + lm;  // each wave: 16 rows
  const float s0 = sv[row0];
  const size_t ar0 = (size_t)row0 * NR;

  f32x4 acc[8];
#pragma unroll
  for (int nn = 0; nn < 8; ++nn) acc[nn] = (f32x4){0.f, 0.f, 0.f, 0.f};
  float l0 = 0.f;

  const int tile0 = sp * 16;  // 16 tiles per split
  // prologue: deep adj prefetch, tiles 0..3 (circular buffer, depth 4)
  int4 A0[4], A1[4];
#pragma unroll
  for (int d = 0; d < 4; ++d) {
    int jd = (tile0 + d) * 32 + q * 8;
    A0[d] = *(const int4*)&adj[ar0 + jd];
    A1[d] = *(const int4*)&adj[ar0 + jd + 4];
  }

#pragma unroll
  for (int t = 0; t < 16; ++t) {
    if ((t & 7) == 0) {  // stage phase: 8 tiles -> 64 KB LDS
      __syncthreads();   // prior phase's readers done
      const int pb = tile0 + t;
#pragma unroll
      for (int z = 0; z < 8; ++z) {
        int id = z * 512 + tid;  // 0..4095 uint4s
        int tt = id >> 9;
        int k = id & 511;
        uint4 v = *(const uint4*)&HT2[(size_t)(pb + tt) * 4096 + k * 8];
        *(uint4*)&lds_s[tt * 4096 + k * 8] = v;
      }
      if (t == 0) ltv[tid] = tv[tile0 * 32 + tid];  // slice tv, once
      __syncthreads();
    }
    // consume prefetched adj for tile t; refill slot with tile t+4
    int4 a00 = A0[t & 3], a01 = A1[t & 3];
    if (t + 4 < 16) {
      int jn = (tile0 + t + 4) * 32 + q * 8;
      A0[t & 3] = *(const int4*)&adj[ar0 + jn];
      A1[t & 3] = *(const int4*)&adj[ar0 + jn + 4];
    }
    // tv + B-frags from LDS only
    float4 tv0 = *(const float4*)&ltv[t * 32 + q * 8];
    float4 tv1 = *(const float4*)&ltv[t * 32 + q * 8 + 4];
    const int tt = t & 7;
    short8 bf[8];
#pragma unroll
    for (int nn = 0; nn < 8; ++nn)
      bf[nn] = *(const short8*)&lds_s[tt * 4096 + (nn * 16 + lm) * 32 + q * 8];

    int av0[8] = {a00.x, a00.y, a00.z, a00.w, a01.x, a01.y, a01.z, a01.w};
    float tvl[8] = {tv0.x, tv0.y, tv0.z, tv0.w, tv1.x, tv1.y, tv1.z, tv1.w};
    short8 p0;
#pragma unroll
    for (int e = 0; e < 8; ++e) {
      // logits pre-scaled by log2e; lrelu(v) = max(v, 0.2v)
      float v0 = s0 + tvl[e];
      float e0 = fmaxf(v0, 0.2f * v0);
      float pp0 = (av0[e] > 0) ? __builtin_amdgcn_exp2f(e0) : 0.f;
      l0 += pp0;
      p0[e] = f2bf(pp0);
    }
#pragma unroll
    for (int nn = 0; nn < 8; ++nn)
      acc[nn] = __builtin_amdgcn_mfma_f32_16x16x32_bf16(p0, bf[nn], acc[nn], 0, 0, 0);
  }
  __syncthreads();  // slice LDS free -> reuse for epilogue

  // epilogue: wave-private LDS transpose (8 KB/wave = 64 KB), contiguous
  // float4 stores. Single-wave region: lgkmcnt orders, no barrier.
  float* my = (float*)lds_s + w * 2048;
#pragma unroll
  for (int nn = 0; nn < 8; ++nn)
#pragma unroll
    for (int r = 0; r < 4; ++r)
      my[(4 * q + r) * 128 + nn * 16 + lm] = acc[nn][r];
  float* pbase = part + ((size_t)sp * NR + i0 + 16 * w) * 128;
#pragma unroll
  for (int c = 0; c < 8; ++c) {
    int idx = (c * 64 + L) * 4;
    *(float4*)&pbase[idx] = *(const float4*)&my[idx];
  }

  // denominator: reduce the 4 q-replicas of each row
  l0 += __shfl_xor(l0, 16);
  l0 += __shfl_xor(l0, 32);
  if (q == 0) lpart[sp * NR + row0] = l0;
}

// ---------------------------------------------------------------------------
// K4: out[i][f] = sum_sp part / sum_sp lpart   (float4 vectorized)
// ---------------------------------------------------------------------------
__global__ __launch_bounds__(256) void k_reduce(const float* __restrict__ part,
                                                const float* __restrict__ lpart,
                                                float* __restrict__ out, int S) {
  int idx4 = blockIdx.x * 256 + threadIdx.x;
  int idx = idx4 * 4;  // i*128+f
  int i = idx >> 7;
  float4 sum = {0.f, 0.f, 0.f, 0.f};
  for (int sp = 0; sp < S; ++sp) {
    float4 v = *(const float4*)&part[(size_t)sp * (NR * 128) + idx];
    sum.x += v.x; sum.y += v.y; sum.z += v.z; sum.w += v.w;
  }
  float l = 0.f;
  for (int sp = 0; sp < S; ++sp) l += lpart[sp * NR + i];
  float inv = (l > 0.f) ? 1.f / l : 0.f;
  float4 o = {sum.x * inv, sum.y * inv, sum.z * inv, sum.w * inv};
  *(float4*)&out[idx] = o;
}

extern "C" void kernel_launch(void* const* d_in, const int* in_sizes, int n_in,
                              void* d_out, int out_size, void* d_ws, size_t ws_size,
                              hipStream_t stream) {
  const float* x = (const float*)d_in[0];    // 8192 x 256 fp32
  const int* adj = (const int*)d_in[1];      // 8192 x 8192 int32
  const float* W = (const float*)d_in[2];    // 256 x 128 fp32
  const float* a = (const float*)d_in[3];    // 256 x 1 fp32
  float* out = (float*)d_out;                // 8192 x 128 fp32

  char* ws = (char*)d_ws;
  short* HT2 = (short*)(ws + 0);          // 2 MB  bf16 h tiled [256][128][32]
  float* sv = (float*)(ws + 2097152);     // 32 KB
  float* tv = (float*)(ws + 2129920);     // 32 KB
  float* lpart = (float*)(ws + 2162688);  // 16*32 KB = 512 KB
  float* part = (float*)(ws + 2719744);   // 16 * 4 MB = 64 MB

  const int S = 16;  // j-splits: 64 i-tiles x 16 = 1024 blocks of 8 waves

  hipLaunchKernelGGL(k_gemm_h, dim3(128), dim3(256), 0, stream, x, W, a, HT2, sv, tv);
  hipLaunchKernelGGL(k_flash, dim3(64 * S), dim3(512), 0, stream, adj, HT2, sv, tv,
                     part, lpart);
  hipLaunchKernelGGL(k_reduce, dim3((NR * 128) / 1024), dim3(256), 0, stream, part,
                     lpart, out, S);
}